// Round 8
// baseline (539.795 us; speedup 1.0000x reference)
//
#include <hip/hip_runtime.h>

#define B_N 4096
#define T_N 64
#define K_N 512
#define D_N 64

// ws layout:
//   [0, 131072)        : used[t*K+k] (32768 uints)
//   [131072, 131080)   : loss_sum (double)
// both zeroed by one hipMemsetAsync.

// Main kernel: one thread per (b,t) row (M=1). z row pinned in VGPRs:
// amdgpu_waves_per_eu(4,4) caps the allocator's occupancy target so it stops
// spilling z to chase unreachable tiers (r4/r5 failure mode). Codebook rows
// are block-uniform -> s_load into SGPRs (scalar broadcast, v_fma v,v,s).
// c2 computed once into LDS by the prologue (uniform ds_read broadcast).
// dist = fl( fl(A - 2*dot) + c2 ), dot = ascending-d FMA chain, strict-< argmin.
// NOTE: asm laundering must use SCALAR float operands -- "+v" on float4 is a
// tied indirect register input, unsupported by the gfx950 backend (r7 compile
// failure).
__global__ __launch_bounds__(256)
__attribute__((amdgpu_waves_per_eu(4, 4)))
void vq_main(const float* __restrict__ z_e,
             const float* __restrict__ cb,
             float* __restrict__ zq_out,
             float* __restrict__ tok_out,
             unsigned* __restrict__ used,
             double* __restrict__ loss_sum) {
    const int t   = blockIdx.y;
    const int tid = threadIdx.x;
    const int b   = blockIdx.x * 256 + tid;

    const float* cbt = cb + (size_t)t * K_N * D_N;

    __shared__ float  c2s[K_N];
    __shared__ double red[256];

    // ---- prologue: c2 for codes 2*tid, 2*tid+1 (pre-rounded squares,
    // sequential ascending-d adds -- matches jnp.sum(c*c, axis=-1)) ----
    {
        const float4* c = reinterpret_cast<const float4*>(cbt) + (size_t)(2 * tid) * 16;
        float s0 = 0.0f, s1 = 0.0f;
#pragma unroll
        for (int j = 0; j < 16; ++j) {
            float4 v0 = c[j];
            float4 v1 = c[16 + j];
            s0 = __fadd_rn(s0, __fmul_rn(v0.x, v0.x));
            s0 = __fadd_rn(s0, __fmul_rn(v0.y, v0.y));
            s0 = __fadd_rn(s0, __fmul_rn(v0.z, v0.z));
            s0 = __fadd_rn(s0, __fmul_rn(v0.w, v0.w));
            s1 = __fadd_rn(s1, __fmul_rn(v1.x, v1.x));
            s1 = __fadd_rn(s1, __fmul_rn(v1.y, v1.y));
            s1 = __fadd_rn(s1, __fmul_rn(v1.z, v1.z));
            s1 = __fadd_rn(s1, __fmul_rn(v1.w, v1.w));
        }
        c2s[2 * tid]     = s0;
        c2s[2 * tid + 1] = s1;
    }

    // ---- z row -> 64 scalar registers, laundered per-element ----
    float z[D_N];
    {
        const float4* zr = reinterpret_cast<const float4*>(z_e + ((size_t)b * T_N + t) * D_N);
#pragma unroll
        for (int j = 0; j < 16; ++j) {
            float4 v = zr[j];
            z[4*j+0] = v.x; z[4*j+1] = v.y; z[4*j+2] = v.z; z[4*j+3] = v.w;
        }
    }
#pragma unroll
    for (int j = 0; j < D_N; ++j) asm volatile("" : "+v"(z[j]));

    // A = sum(z*z): pre-rounded products, sequential ascending-d adds.
    float A = 0.0f;
#pragma unroll
    for (int j = 0; j < D_N; ++j) A = __fadd_rn(A, __fmul_rn(z[j], z[j]));

    __syncthreads();   // c2s ready

    // ---- main loop: codebook row via uniform scalar loads ----
    float best = __builtin_inff();
    int tok = 0;
#pragma unroll 2
    for (int k = 0; k < K_N; ++k) {
        const float* crow = cbt + k * D_N;   // block-uniform -> s_load
        float a = 0.0f;
#pragma unroll
        for (int j = 0; j < D_N; ++j) a = __builtin_fmaf(z[j], crow[j], a);
        float dist = __fadd_rn(__fsub_rn(A, __fmul_rn(2.0f, a)), c2s[k]);
        if (dist < best) { best = dist; tok = k; }   // strict <: first-occurrence ties
    }

    // ---- epilogue: z_q_st = winning codebook row; loss in double ----
    const float4* q = reinterpret_cast<const float4*>(cbt + (size_t)tok * D_N);
    float4* zq = reinterpret_cast<float4*>(zq_out + ((size_t)b * T_N + t) * D_N);
    double ld = 0.0;
#pragma unroll
    for (int j = 0; j < 16; ++j) {
        float4 qv = q[j];
        zq[j] = qv;
        float d0 = z[4*j+0] - qv.x, d1 = z[4*j+1] - qv.y;
        float d2 = z[4*j+2] - qv.z, d3 = z[4*j+3] - qv.w;
        ld += (double)d0 * d0 + (double)d1 * d1 + (double)d2 * d2 + (double)d3 * d3;
    }
    tok_out[(size_t)b * T_N + t] = (float)tok;
    used[t * K_N + tok] = 1u;

    red[tid] = ld;
    __syncthreads();
    for (int s = 128; s > 0; s >>= 1) {
        if (tid < s) red[tid] += red[tid + s];
        __syncthreads();
    }
    if (tid == 0) atomicAdd(loss_sum, red[0]);
}

__global__ __launch_bounds__(1024) void finalize_kernel(const unsigned* __restrict__ used,
                                                        const double* __restrict__ loss_sum,
                                                        float* __restrict__ out) {
    __shared__ unsigned s[1024];
    const uint4* u4 = reinterpret_cast<const uint4*>(used);
    unsigned c = 0;
#pragma unroll
    for (int i = 0; i < 8; ++i) {
        uint4 v = u4[threadIdx.x + i * 1024];
        c += v.x + v.y + v.z + v.w;
    }
    s[threadIdx.x] = c;
    __syncthreads();
    for (int st = 512; st > 0; st >>= 1) {
        if (threadIdx.x < st) s[threadIdx.x] += s[threadIdx.x + st];
        __syncthreads();
    }
    if (threadIdx.x == 0) {
        const size_t base = (size_t)B_N * T_N * D_N + (size_t)B_N * T_N;
        out[base]     = (float)(0.25 * (*loss_sum) / (double)((size_t)B_N * T_N * D_N));
        out[base + 1] = (float)s[0] / (float)(T_N * K_N);
    }
}

extern "C" void kernel_launch(void* const* d_in, const int* in_sizes, int n_in,
                              void* d_out, int out_size, void* d_ws, size_t ws_size,
                              hipStream_t stream) {
    const float* z_e = (const float*)d_in[0];
    const float* cb  = (const float*)d_in[1];
    float* out = (float*)d_out;

    unsigned* used = (unsigned*)d_ws;
    double*   loss = (double*)((char*)d_ws + 131072);

    (void)hipMemsetAsync(used, 0, 131072 + 8, stream);

    float* tok_out = out + (size_t)B_N * T_N * D_N;
    vq_main<<<dim3(B_N / 256, T_N), 256, 0, stream>>>(z_e, cb, out, tok_out, used, loss);

    finalize_kernel<<<1, 1024, 0, stream>>>(used, loss, out);
}